// Round 1
// baseline (147.235 us; speedup 1.0000x reference)
//
#include <hip/hip_runtime.h>
#include <hip/hip_bf16.h>

// world_state_encoder: out[b, beaker*4+slot, :] = color_emb[X[b, beaker*5+1+slot], :]
// B=32768, 7 beakers, 4 color slots, D=128 -> out is [B, 3584] f32.
// Pure gather + stream-out: write-BW bound (~470 MB out, ~4.6 MB idx in).

#define NUM_BEAKERS 7
#define ENTRIES_PER_BEAKER 5
#define COLOR_DIM 128
#define GROUPS 28                 // 7 beakers * 4 color slots
#define F4_PER_ROW (GROUPS * COLOR_DIM / 4)   // 28*32 = 896 float4 per row

__global__ __launch_bounds__(F4_PER_ROW) void world_state_encoder_kernel(
        const int* __restrict__ X,          // [B, 35] int32
        const float* __restrict__ emb,      // [7, 128] f32
        float* __restrict__ out,            // [B, 3584] f32
        int B) {
    const int b = blockIdx.x;
    const int t = threadIdx.x;              // 0..895

    __shared__ int ids[GROUPS];
    if (t < GROUPS) {
        const int beaker = t >> 2;          // t/4
        const int slot   = t & 3;           // t%4
        ids[t] = X[b * (NUM_BEAKERS * ENTRIES_PER_BEAKER) + beaker * ENTRIES_PER_BEAKER + 1 + slot];
    }
    __syncthreads();

    const int g  = t >> 5;                  // which of the 28 gathered vectors (0..27)
    const int d4 = t & 31;                  // float4 index within the 128-f32 vector (0..31)
    const int id = ids[g];                  // LDS broadcast within each 32-lane group

    const float4 v = reinterpret_cast<const float4*>(emb)[id * (COLOR_DIM / 4) + d4];
    reinterpret_cast<float4*>(out)[(size_t)b * F4_PER_ROW + t] = v;
}

extern "C" void kernel_launch(void* const* d_in, const int* in_sizes, int n_in,
                              void* d_out, int out_size, void* d_ws, size_t ws_size,
                              hipStream_t stream) {
    const int*   X   = (const int*)d_in[0];     // [B, 35] int32
    const float* emb = (const float*)d_in[1];   // [7, 128] f32
    float*       out = (float*)d_out;           // [B, 3584] f32

    const int B = in_sizes[0] / (NUM_BEAKERS * ENTRIES_PER_BEAKER);  // 32768

    world_state_encoder_kernel<<<B, F4_PER_ROW, 0, stream>>>(X, emb, out, B);
}

// Round 2
// 109.937 us; speedup vs baseline: 1.3393x; 1.3393x over previous
//
#include <hip/hip_runtime.h>
#include <hip/hip_bf16.h>

// world_state_encoder: out[b, beaker*4+slot, :] = color_emb[X[b, beaker*5+1+slot], :]
// B=32768, 7 beakers, 4 color slots, D=128 -> out is [B, 3584] f32.
// Pure gather + stream-out: write-BW bound (~470 MB out, ~4.6 MB idx in).
//
// R2: persistent blocks + grid-stride over rows. R1 (one block per row) was
// latency/launch-bound at 3.2 TB/s: each wave did 1 store then died, plus a
// barrier. Now 512 blocks x 896 threads loop over 64 rows each with no
// barrier and no LDS; per-thread (g,d4) and the output column are
// loop-invariant, X-row reads are L1-broadcast hits, emb (3.5 KB) is
// L1-resident, and unroll-4 keeps 4 independent float4 stores in flight.

#define NUM_BEAKERS 7
#define ENTRIES_PER_BEAKER 5
#define ROW_INTS (NUM_BEAKERS * ENTRIES_PER_BEAKER)   // 35
#define COLOR_DIM 128
#define GROUPS 28                                     // 7 beakers * 4 color slots
#define F4_PER_ROW (GROUPS * COLOR_DIM / 4)           // 28*32 = 896 float4 per row

__global__ __launch_bounds__(F4_PER_ROW, 7) void world_state_encoder_kernel(
        const int* __restrict__ X,          // [B, 35] int32
        const float* __restrict__ emb,      // [7, 128] f32
        float* __restrict__ out,            // [B, 3584] f32
        int B) {
    const int t  = threadIdx.x;             // 0..895
    const int g  = t >> 5;                  // gathered-vector index 0..27
    const int d4 = t & 31;                  // float4 index within the 128-f32 vector

    // loop-invariant offsets
    const int xoff = (g >> 2) * ENTRIES_PER_BEAKER + (g & 3) + 1;  // within the 35-int row
    const float4* __restrict__ embf4 = reinterpret_cast<const float4*>(emb);
    float4* __restrict__ outf4 = reinterpret_cast<float4*>(out);

    #pragma unroll 4
    for (int b = blockIdx.x; b < B; b += gridDim.x) {
        const int id = X[b * ROW_INTS + xoff];          // L1-broadcast hit
        const float4 v = embf4[id * (COLOR_DIM / 4) + d4];  // L1 hit (3.5 KB table)
        outf4[(size_t)b * F4_PER_ROW + t] = v;          // coalesced 14336 B per block-iter
    }
}

extern "C" void kernel_launch(void* const* d_in, const int* in_sizes, int n_in,
                              void* d_out, int out_size, void* d_ws, size_t ws_size,
                              hipStream_t stream) {
    const int*   X   = (const int*)d_in[0];     // [B, 35] int32
    const float* emb = (const float*)d_in[1];   // [7, 128] f32
    float*       out = (float*)d_out;           // [B, 3584] f32

    const int B = in_sizes[0] / ROW_INTS;       // 32768

    const int grid = (B < 512) ? B : 512;       // 2 blocks/CU resident, 28 waves/CU
    world_state_encoder_kernel<<<grid, F4_PER_ROW, 0, stream>>>(X, emb, out, B);
}

// Round 3
// 96.799 us; speedup vs baseline: 1.5210x; 1.1357x over previous
//
#include <hip/hip_runtime.h>
#include <hip/hip_bf16.h>

// world_state_encoder: out[b, beaker*4+slot, :] = color_emb[X[b, beaker*5+1+slot], :]
// B=32768, 7 beakers, 4 color slots, D=128 -> out is [B, 3584] f32.
// Write-BW bound: ~470 MB out vs 4.6 MB idx in. Demonstrated ceiling on this
// chip: harness memset hits 6.8-7.0 TB/s -> floor ~70 us.
//
// R3: decouple index loads from the store stream. Each block owns a
// contiguous 64-row chunk: stage the raw X slice (64*35 ints = 8960 B) into
// LDS with ONE coalesced read + one barrier, then run a barrier-free store
// loop whose only deps are an LDS broadcast (free, same-addr per 32 lanes)
// and an L1-resident emb float4. Unroll 8 => 8 independent store chains per
// thread. R2 (global X-load in-loop, stride-512 rows) kept every store gated
// behind a cold ~200-900cy global load: 4.3 TB/s. This removes that gate.

#define NUM_BEAKERS 7
#define ENTRIES_PER_BEAKER 5
#define ROW_INTS (NUM_BEAKERS * ENTRIES_PER_BEAKER)   // 35
#define COLOR_DIM 128
#define GROUPS 28                                     // 7 beakers * 4 color slots
#define F4_PER_ROW (GROUPS * COLOR_DIM / 4)           // 28*32 = 896 float4 per row
#define NTHREADS F4_PER_ROW                           // 896 = 14 waves
#define CHUNK 64                                      // rows per block

__global__ __launch_bounds__(NTHREADS, 7) void world_state_encoder_kernel(
        const int* __restrict__ X,          // [B, 35] int32
        const float* __restrict__ emb,      // [7, 128] f32
        float* __restrict__ out,            // [B, 3584] f32
        int B) {
    const int t  = threadIdx.x;             // 0..895
    const int g  = t >> 5;                  // gathered-vector index 0..27
    const int d4 = t & 31;                  // float4 index within the 128-f32 vector
    const int xoff = (g >> 2) * ENTRIES_PER_BEAKER + (g & 3) + 1;  // within a 35-int row

    __shared__ int xs[CHUNK * ROW_INTS];    // 8960 B raw X slice for this chunk

    const float4* __restrict__ embf4 = reinterpret_cast<const float4*>(emb);
    float4* __restrict__ outf4 = reinterpret_cast<float4*>(out);

    for (int b0 = blockIdx.x * CHUNK; b0 < B; b0 += gridDim.x * CHUNK) {
        const int rows  = min(CHUNK, B - b0);
        const int nints = rows * ROW_INTS;

        __syncthreads();                    // xs reuse guard (no-op on first pass)
        for (int i = t; i < nints; i += NTHREADS)
            xs[i] = X[b0 * ROW_INTS + i];   // one coalesced 8960 B read
        __syncthreads();

        float4* __restrict__ dst = outf4 + (size_t)b0 * F4_PER_ROW + t;
        #pragma unroll 8
        for (int r = 0; r < rows; ++r) {
            const int id = xs[r * ROW_INTS + xoff];        // LDS broadcast
            const float4 v = embf4[id * (COLOR_DIM / 4) + d4];  // L1 hit (3.5 KB table)
            dst[(size_t)r * F4_PER_ROW] = v;               // coalesced stream-out
        }
    }
}

extern "C" void kernel_launch(void* const* d_in, const int* in_sizes, int n_in,
                              void* d_out, int out_size, void* d_ws, size_t ws_size,
                              hipStream_t stream) {
    const int*   X   = (const int*)d_in[0];     // [B, 35] int32
    const float* emb = (const float*)d_in[1];   // [7, 128] f32
    float*       out = (float*)d_out;           // [B, 3584] f32

    const int B = in_sizes[0] / ROW_INTS;       // 32768

    const int nchunks = (B + CHUNK - 1) / CHUNK;    // 512 for B=32768
    const int grid = (nchunks < 512) ? nchunks : 512;
    world_state_encoder_kernel<<<grid, NTHREADS, 0, stream>>>(X, emb, out, B);
}